// Round 14
// baseline (553.702 us; speedup 1.0000x reference)
//
#include <hip/hip_runtime.h>

#define N_NODES 50000
#define N_EDGES 800000
#define NODE_DIM 128
#define EDGE_DIM 64
#define HIDDEN 256
#define K_N 192   // NODE_DIM + EDGE_DIM

typedef __attribute__((ext_vector_type(8))) short bf16x8;
typedef __attribute__((ext_vector_type(4))) float f32x4;
typedef __attribute__((ext_vector_type(16))) float f32x16;
typedef unsigned short u16;
typedef unsigned int u32;

#define MFMA16 __builtin_amdgcn_mfma_f32_16x16x32_bf16
#define MFMA32 __builtin_amdgcn_mfma_f32_32x32x16_bf16

__device__ inline u16 f2bf(float f) {
  u32 u = __builtin_bit_cast(u32, f);
  u += 0x7fffu + ((u >> 16) & 1u);
  return (u16)(u >> 16);
}
__device__ inline float bf2f(u16 u) {
  u32 x = ((u32)u) << 16;
  return __builtin_bit_cast(float, x);
}
// HW packed f32->bf16 (RNE), lo = a, hi = b
__device__ inline u32 cvt_pk(float a, float b) {
  u32 r;
  asm("v_cvt_pk_bf16_f32 %0, %1, %2" : "=v"(r) : "v"(a), "v"(b));
  return r;
}
__device__ inline void st_bf4(u16* p, float4 v) {
  ushort4 r;
  r.x = f2bf(v.x); r.y = f2bf(v.y); r.z = f2bf(v.z); r.w = f2bf(v.w);
  *reinterpret_cast<ushort4*>(p) = r;
}

// ---------------- weight prep (+ fused degree histogram) ----------------
__global__ void prep_weights(const float* __restrict__ We1, const float* __restrict__ We2,
                             const float* __restrict__ Wn1, const float* __restrict__ Wn2,
                             const float* __restrict__ be2, const int* __restrict__ dst,
                             u16* __restrict__ w1st, u16* __restrict__ w1dt,
                             u16* __restrict__ w1ef, u16* __restrict__ w2y,
                             u16* __restrict__ wn1t, u16* __restrict__ wn2t,
                             float* __restrict__ b2p, int* __restrict__ hist) {
  const int stride = gridDim.x * blockDim.x;
  const int tid = blockIdx.x * blockDim.x + threadIdx.x;
  for (int i = tid; i < HIDDEN * NODE_DIM; i += stride) {
    int h = i >> 7, k = i & 127;
    w1st[i] = f2bf(We1[k * HIDDEN + h]);
    w1dt[i] = f2bf(We1[(192 + k) * HIDDEN + h]);
  }
  for (int i = tid; i < 8 * 4 * 64 * 8; i += stride) {
    int jj = i & 7;
    int l = (i >> 3) & 63;
    int kb = (i >> 9) & 3;
    int ht = i >> 11;
    int h = ht * 32 + (l & 31);
    int kloc = kb * 16 + (l >> 5) * 8 + jj;
    w1ef[i] = f2bf(We1[(128 + kloc) * HIDDEN + h]);
  }
  for (int i = tid; i < EDGE_DIM * HIDDEN; i += stride) {
    int jj = i & 7;
    int l = (i >> 3) & 63;
    int t2 = (i >> 9) & 1;
    int kb2 = i >> 10;
    int out = t2 * 32 + (l & 31);
    int hi = l >> 5;
    int k = kb2 * 16 + (jj & 3) + 8 * (jj >> 2) + 4 * hi;
    w2y[i] = f2bf(We2[k * EDGE_DIM + out]);
  }
  for (int i = tid; i < HIDDEN * K_N; i += stride) {
    int n = i / K_N, k = i % K_N;
    wn1t[i] = f2bf(Wn1[k * HIDDEN + n]);
  }
  for (int i = tid; i < NODE_DIM * HIDDEN; i += stride) {
    int n = i / HIDDEN, k = i % HIDDEN;
    wn2t[i] = f2bf(Wn2[k * NODE_DIM + n]);
  }
  for (int i = tid; i < EDGE_DIM; i += stride) {
    int t2 = i >> 5, hi = (i >> 4) & 1, r = i & 15;
    b2p[i] = be2[t2 * 32 + (r & 3) + 8 * (r >> 2) + 4 * hi];
  }
  for (int i = tid; i < N_EDGES; i += stride)
    atomicAdd(&hist[dst[i]], 1);
}

// ---------------- P-GEMM (fused: both tables per block) ----------------
// P[n][c], c = hi*128 + ht*16 + r  <->  h = ht*32 + (r&3) + 8*(r>>2) + 4*hi.
#define NB_P 782   // ceil(50000/64)
#define SA_P 136
#define SH   264

__global__ __launch_bounds__(256) void pgemm_kernel(
    const float* __restrict__ nf, const u16* __restrict__ w1st,
    const u16* __restrict__ w1dt, const float* __restrict__ be1,
    u16* __restrict__ P_src, u16* __restrict__ P_dst)
{
  __shared__ u16 A[64 * SA_P];
  __shared__ u16 H[64 * SH];
  const int tid = threadIdx.x;
  const int n0 = blockIdx.x * 64;
  const float4* nf4 = reinterpret_cast<const float4*>(nf);

  #pragma unroll
  for (int p = 0; p < 8; ++p) {
    int i = p * 256 + tid;
    int row = i >> 5, c4 = i & 31;
    int rg = min(n0 + row, N_NODES - 1);
    float4 v = nf4[(size_t)rg * 32 + c4];
    st_bf4(&A[row * SA_P + c4 * 4], v);
  }
  __syncthreads();

  const int wave = tid >> 6, lane = tid & 63;
  const int lr = lane & 15;
  const int lk = (lane >> 4) * 8;

  for (int table = 0; table < 2; ++table) {
    const u16* w = table ? w1dt : w1st;
    u16* P = table ? P_dst : P_src;

    f32x4 acc[4][4] = {};
    #pragma unroll
    for (int kb = 0; kb < 4; ++kb) {
      const int ko = kb * 32 + lk;
      bf16x8 a[4], bb[4];
      #pragma unroll
      for (int mt = 0; mt < 4; ++mt)
        a[mt] = *reinterpret_cast<const bf16x8*>(&A[(mt * 16 + lr) * SA_P + ko]);
      #pragma unroll
      for (int nt = 0; nt < 4; ++nt)
        bb[nt] = *reinterpret_cast<const bf16x8*>(&w[(size_t)(wave * 64 + nt * 16 + lr) * 128 + ko]);
      #pragma unroll
      for (int mt = 0; mt < 4; ++mt)
        #pragma unroll
        for (int nt = 0; nt < 4; ++nt)
          acc[mt][nt] = MFMA16(a[mt], bb[nt], acc[mt][nt], 0, 0, 0);
    }
    __syncthreads();   // H write-after-read across tables

    #pragma unroll
    for (int mt = 0; mt < 4; ++mt)
      #pragma unroll
      for (int nt = 0; nt < 4; ++nt) {
        int col = wave * 64 + nt * 16 + lr;
        float bias = table ? 0.f : be1[col];
        #pragma unroll
        for (int j = 0; j < 4; ++j) {
          int row = mt * 16 + (lane >> 4) * 4 + j;
          H[row * SH + col] = f2bf(acc[mt][nt][j] + bias);  // no relu: pre-act partial
        }
      }
    __syncthreads();

    #pragma unroll
    for (int p = 0; p < 16; ++p) {
      int u = p * 256 + tid;
      int row = u >> 6, cg = u & 63;
      int hi = cg >> 5, ht = (cg >> 2) & 7, q = cg & 3;
      int hbase = ht * 32 + 8 * q + 4 * hi;
      int n = n0 + row;
      if (n < N_NODES) {
        ushort4 v = *reinterpret_cast<const ushort4*>(&H[row * SH + hbase]);
        *reinterpret_cast<ushort4*>(&P[(size_t)n * 256 + cg * 4]) = v;
      }
    }
  }
}

// ---------------- CSR build: 3-phase parallel scan ----------------
#define NB_SCAN 196   // 196*256 = 50176 >= 50000

__global__ void scanA_kernel(const int* __restrict__ hist, int* __restrict__ eid) {
  __shared__ int red[256];
  int gid = blockIdx.x * 256 + threadIdx.x;
  int v = (gid < N_NODES) ? hist[gid] : 0;
  red[threadIdx.x] = v;
  __syncthreads();
  for (int d = 128; d > 0; d >>= 1) {
    if (threadIdx.x < d) red[threadIdx.x] += red[threadIdx.x + d];
    __syncthreads();
  }
  if (threadIdx.x == 0) eid[blockIdx.x] = red[0];   // bsum[b]
}

__global__ void scanB_kernel(int* __restrict__ eid, int* __restrict__ off) {
  __shared__ int ssum[256];
  int tid = threadIdx.x;
  int v = (tid < NB_SCAN) ? eid[tid] : 0;
  ssum[tid] = v;
  __syncthreads();
  for (int d = 1; d < 256; d <<= 1) {
    int t = (tid >= d) ? ssum[tid - d] : 0;
    __syncthreads();
    ssum[tid] += t;
    __syncthreads();
  }
  if (tid < NB_SCAN) eid[256 + tid] = ssum[tid] - v;   // bpre[b] (exclusive)
  if (tid == 255) off[N_NODES] = ssum[255];            // total
}

__global__ void scanC_kernel(const int* __restrict__ hist, const int* __restrict__ eid,
                             int* __restrict__ off, int* __restrict__ cursor,
                             float* __restrict__ e_sum) {
  __shared__ int ssum[256];
  int tid = threadIdx.x;
  int gid = blockIdx.x * 256 + tid;
  int base = eid[256 + blockIdx.x];
  int v = (gid < N_NODES) ? hist[gid] : 0;
  ssum[tid] = v;
  __syncthreads();
  for (int d = 1; d < 256; d <<= 1) {
    int t = (tid >= d) ? ssum[tid - d] : 0;
    __syncthreads();
    ssum[tid] += t;
    __syncthreads();
  }
  if (gid < N_NODES) {
    int o = base + ssum[tid] - v;
    off[gid] = o;
    cursor[gid] = o;
    float4 z = {0.f, 0.f, 0.f, 0.f};
    float4* ez = reinterpret_cast<float4*>(e_sum + (size_t)gid * 64);
    #pragma unroll
    for (int q = 0; q < 16; ++q) ez[q] = z;
  }
}

// scatter: emits csr_src/csr_dst; EFB: also CSR-ordered bf16 edge features
// (full-128B-line scattered writes, no RMW); else eid for the gather fallback.
template<bool EFB>
__global__ void scatter_kernel(const int* __restrict__ src, const int* __restrict__ dst,
                               const float* __restrict__ ef,
                               int* __restrict__ cursor, int* __restrict__ eid,
                               int* __restrict__ csr_src, int* __restrict__ csr_dst,
                               u16* __restrict__ csr_efb) {
  int e = blockIdx.x * blockDim.x + threadIdx.x;
  if (e < N_EDGES) {
    int d = dst[e];
    int pos = atomicAdd(&cursor[d], 1);
    csr_src[pos] = src[e];
    csr_dst[pos] = d;
    if (EFB) {
      const float4* s = reinterpret_cast<const float4*>(ef + (size_t)e * 64);
      #pragma unroll
      for (int q = 0; q < 16; q += 2) {
        float4 v0 = s[q], v1 = s[q + 1];
        uint4 r;
        r.x = cvt_pk(v0.x, v0.y); r.y = cvt_pk(v0.z, v0.w);
        r.z = cvt_pk(v1.x, v1.y); r.w = cvt_pk(v1.z, v1.w);
        *reinterpret_cast<uint4*>(csr_efb + (size_t)pos * 64 + q * 4) = r;
      }
    } else {
      eid[pos] = e;
    }
  }
}

// ---------------- edge MLP v11: K=64 split + coalesced CSR edge feats --------
// layer1 = P_src[src] + P_dst[dst] + e @ W1e. P gathers software-pipelined
// (prefetch ht+1 while MFMAing ht). H-pack via v_cvt_pk_bf16_f32.
template<bool EFB>
__global__ __launch_bounds__(256, 4) void edge_mlp(
    const u16* __restrict__ P_src, const u16* __restrict__ P_dst,
    const float* __restrict__ ef, const u16* __restrict__ csr_efb,
    const int* __restrict__ eid, const int* __restrict__ csr_src,
    const int* __restrict__ csr_dst,
    const u16* __restrict__ w1ef, const u16* __restrict__ w2y,
    const float* __restrict__ b2p,
    float* __restrict__ e_sum, float* __restrict__ out_edge)
{
  __shared__ char shmem[33280];                     // 33,280 B (4 blocks/CU ok)
  u16* W1e = reinterpret_cast<u16*>(shmem);         // 32,768 B (phase 1)
  float* bounce = reinterpret_cast<float*>(shmem);  // 128x65 f32 (phase 2, aliased)

  const int tid = threadIdx.x;
  const int wv = tid >> 6, lane = tid & 63;
  const int ecol = lane & 31;     // CSR position within wave tile (D col)
  const int hi = lane >> 5;       // k half
  const int e0 = blockIdx.x * 128;
  const int pos = e0 + wv * 32 + ecol;

  // ---- stage W1e fragments (32KB, once) ----
  {
    const uint4* s = reinterpret_cast<const uint4*>(w1ef);
    uint4* d = reinterpret_cast<uint4*>(W1e);
    #pragma unroll
    for (int j = 0; j < 8; ++j) d[j * 256 + tid] = s[j * 256 + tid];
  }

  // ---- fused edge-feature passthrough (identity, fp32, fully coalesced) ----
  {
    const float4* ef4 = reinterpret_cast<const float4*>(ef);
    float4* oe4 = reinterpret_cast<float4*>(out_edge);
    #pragma unroll
    for (int p = 0; p < 8; ++p) {
      size_t i = (size_t)e0 * 16 + p * 256 + tid;
      oe4[i] = ef4[i];
    }
  }

  // ---- CSR indices (coalesced) ----
  const int srcn = csr_src[pos];
  const int dstn = csr_dst[pos];   // register; shfl'd in the epilogue

  // ---- edge features -> B-frags (k = kb*16 + hi*8 + jj), K=64 ----
  bf16x8 efr[4];
  if (EFB) {
    const u16* eb = csr_efb + (size_t)pos * 64 + hi * 8;   // coalesced bf16
    #pragma unroll
    for (int kb = 0; kb < 4; ++kb)
      efr[kb] = *reinterpret_cast<const bf16x8*>(eb + kb * 16);
  } else {
    const int e = eid[pos];
    #pragma unroll
    for (int kb = 0; kb < 4; ++kb) {
      const float* ep = ef + (size_t)e * 64 + kb * 16 + hi * 8;
      float4 lo = *reinterpret_cast<const float4*>(ep);
      float4 hv = *reinterpret_cast<const float4*>(ep + 4);
      u32 w[4];
      w[0] = cvt_pk(lo.x, lo.y); w[1] = cvt_pk(lo.z, lo.w);
      w[2] = cvt_pk(hv.x, hv.y); w[3] = cvt_pk(hv.z, hv.w);
      efr[kb] = __builtin_bit_cast(bf16x8, *reinterpret_cast<uint4*>(w));
    }
  }

  __syncthreads();   // W1e staged

  // ---- layer-2 accumulators, bias-initialized ----
  f32x16 acc2[2];
  #pragma unroll
  for (int t2 = 0; t2 < 2; ++t2) {
    const float* bp = b2p + t2 * 32 + hi * 16;
    #pragma unroll
    for (int r = 0; r < 16; ++r) acc2[t2][r] = bp[r];
  }

  const u16* psb = P_src + (size_t)srcn * 256 + hi * 128;
  const u16* pdb = P_dst + (size_t)dstn * 256 + hi * 128;

  // prologue P gather (ht=0)
  bf16x8 pa0 = *reinterpret_cast<const bf16x8*>(psb);
  bf16x8 pa1 = *reinterpret_cast<const bf16x8*>(psb + 8);
  bf16x8 pd0 = *reinterpret_cast<const bf16x8*>(pdb);
  bf16x8 pd1 = *reinterpret_cast<const bf16x8*>(pdb + 8);

  // ---- ht loop: 8 tiles of 32 hidden; P gathers pipelined 1 ahead ----
  #pragma unroll
  for (int ht = 0; ht < 8; ++ht) {
    bf16x8 na0, na1, nd0, nd1;
    if (ht < 7) {
      na0 = *reinterpret_cast<const bf16x8*>(psb + (ht + 1) * 16);
      na1 = *reinterpret_cast<const bf16x8*>(psb + (ht + 1) * 16 + 8);
      nd0 = *reinterpret_cast<const bf16x8*>(pdb + (ht + 1) * 16);
      nd1 = *reinterpret_cast<const bf16x8*>(pdb + (ht + 1) * 16 + 8);
    }

    f32x16 acc;
    #pragma unroll
    for (int r = 0; r < 8; ++r) {
      acc[r]     = bf2f((u16)pa0[r]) + bf2f((u16)pd0[r]);
      acc[8 + r] = bf2f((u16)pa1[r]) + bf2f((u16)pd1[r]);
    }

    // layer 1: K=64 (4 kb), W1e frags from LDS
    #pragma unroll
    for (int kb = 0; kb < 4; ++kb) {
      bf16x8 wf = *reinterpret_cast<const bf16x8*>(W1e + ((ht * 4 + kb) * 64 + lane) * 8);
      acc = MFMA32(wf, efr[kb], acc, 0, 0, 0);
    }

    // layer 2: relu + HW-packed bf16 -> B-frag slots (pi matches D row layout)
    #pragma unroll
    for (int s2 = 0; s2 < 2; ++s2) {
      bf16x8 hf;
      u32* hw = reinterpret_cast<u32*>(&hf);
      #pragma unroll
      for (int m = 0; m < 4; ++m)
        hw[m] = cvt_pk(fmaxf(acc[s2 * 8 + 2 * m], 0.f),
                       fmaxf(acc[s2 * 8 + 2 * m + 1], 0.f));
      #pragma unroll
      for (int t2 = 0; t2 < 2; ++t2) {
        bf16x8 wf2 = *reinterpret_cast<const bf16x8*>(
            w2y + ((size_t)((ht * 2 + s2) * 2 + t2) * 64 + lane) * 8);
        acc2[t2] = MFMA32(wf2, hf, acc2[t2], 0, 0, 0);
      }
    }

    pa0 = na0; pa1 = na1; pd0 = nd0; pd1 = nd1;
  }

  __syncthreads();   // all waves done reading W1e before bounce aliasing

  // ---- f32 message bounce: wave-private rows, stride 65 (conflict-free) ----
  {
    const int lp = wv * 32 + ecol;
    #pragma unroll
    for (int t2 = 0; t2 < 2; ++t2)
      #pragma unroll
      for (int r = 0; r < 16; ++r) {
        int o = t2 * 32 + (r & 3) + 8 * (r >> 2) + 4 * hi;
        bounce[lp * 65 + o] = acc2[t2][r];
      }
  }
  // same-wave ds_write -> ds_read: lgkmcnt ordering suffices (no barrier)

  // ---- wave-uniform run-reduction over this wave's 32 positions ----
  {
    const int d = lane;            // dim 0..63
    const int base = wv * 32;      // strip of 32 local positions
    float s = bounce[base * 65 + d];
    int cur = __shfl(dstn, 0, 64);
    #pragma unroll 4
    for (int i = 1; i < 32; ++i) {
      int nx = __shfl(dstn, i, 64);   // wave-uniform
      float v = bounce[(base + i) * 65 + d];
      if (nx == cur) {
        s += v;
      } else {
        atomicAdd(&e_sum[(size_t)cur * 64 + d], s);
        cur = nx;
        s = v;
      }
    }
    atomicAdd(&e_sum[(size_t)cur * 64 + d], s);
  }
}

// ---------------- node MLP + degree gate ----------------
#define SA_N 200

__global__ __launch_bounds__(256) void node_kernel(
    const float* __restrict__ nf, const float* __restrict__ e_sum,
    const int* __restrict__ hist,
    const u16* __restrict__ w1, const float* __restrict__ b1,
    const u16* __restrict__ w2, const float* __restrict__ b2,
    float* __restrict__ hout)
{
  __shared__ u16 A[64 * SH];
  const int tid = threadIdx.x;
  const int n0 = blockIdx.x * 64;

  const float4* nf4 = reinterpret_cast<const float4*>(nf);
  const float4* es4 = reinterpret_cast<const float4*>(e_sum);

  #pragma unroll
  for (int p = 0; p < 8; ++p) {
    int i = p * 256 + tid;
    int row = i >> 5, c4 = i & 31;
    int rg = min(n0 + row, N_NODES - 1);
    float4 v = nf4[(size_t)rg * 32 + c4];
    st_bf4(&A[row * SA_N + c4 * 4], v);
  }
  #pragma unroll
  for (int p = 0; p < 4; ++p) {
    int i = p * 256 + tid;
    int row = i >> 4, c4 = i & 15;
    int rg = min(n0 + row, N_NODES - 1);
    float4 v = es4[(size_t)rg * 16 + c4];
    st_bf4(&A[row * SA_N + 128 + c4 * 4], v);
  }
  __syncthreads();

  const int wave = tid >> 6, lane = tid & 63;
  const int lr = lane & 15;
  const int lk = (lane >> 4) * 8;

  f32x4 acc[4][4] = {};
  for (int kb = 0; kb < K_N / 32; ++kb) {
    const int ko = kb * 32 + lk;
    bf16x8 a[4], b[4];
    #pragma unroll
    for (int mt = 0; mt < 4; ++mt)
      a[mt] = *reinterpret_cast<const bf16x8*>(&A[(mt * 16 + lr) * SA_N + ko]);
    #pragma unroll
    for (int nt = 0; nt < 4; ++nt)
      b[nt] = *reinterpret_cast<const bf16x8*>(&w1[(size_t)(wave * 64 + nt * 16 + lr) * K_N + ko]);
    #pragma unroll
    for (int mt = 0; mt < 4; ++mt)
      #pragma unroll
      for (int nt = 0; nt < 4; ++nt)
        acc[mt][nt] = MFMA16(a[mt], b[nt], acc[mt][nt], 0, 0, 0);
  }
  __syncthreads();

  u16* H = A;
  #pragma unroll
  for (int mt = 0; mt < 4; ++mt)
    #pragma unroll
    for (int nt = 0; nt < 4; ++nt) {
      int col = wave * 64 + nt * 16 + lr;
      float bias = b1[col];
      #pragma unroll
      for (int j = 0; j < 4; ++j) {
        int row = mt * 16 + (lane >> 4) * 4 + j;
        float h = acc[mt][nt][j] + bias;
        H[row * SH + col] = f2bf(h > 0.f ? h : 0.f);
      }
    }
  __syncthreads();

  f32x4 acc2[8] = {};
  for (int kb = 0; kb < HIDDEN / 32; ++kb) {
    const int ko = kb * 32 + lk;
    bf16x8 a = *reinterpret_cast<const bf16x8*>(&H[(wave * 16 + lr) * SH + ko]);
    #pragma unroll
    for (int nt = 0; nt < 8; ++nt) {
      bf16x8 b = *reinterpret_cast<const bf16x8*>(&w2[(size_t)(nt * 16 + lr) * HIDDEN + ko]);
      acc2[nt] = MFMA16(a, b, acc2[nt], 0, 0, 0);
    }
  }
  #pragma unroll
  for (int nt = 0; nt < 8; ++nt) {
    int col = nt * 16 + lr;
    float bias = b2[col];
    #pragma unroll
    for (int j = 0; j < 4; ++j) {
      int row = wave * 16 + (lane >> 4) * 4 + j;
      int rg = n0 + row;
      if (rg < N_NODES) {
        float v = acc2[nt][j] + bias;
        hout[(size_t)rg * NODE_DIM + col] =
            (hist[rg] != 0) ? v : nf[(size_t)rg * NODE_DIM + col];
      }
    }
  }
}

// ---------------- launcher ----------------
extern "C" void kernel_launch(void* const* d_in, const int* in_sizes, int n_in,
                              void* d_out, int out_size, void* d_ws, size_t ws_size,
                              hipStream_t stream) {
  const float* nf  = (const float*)d_in[0];
  const float* ef  = (const float*)d_in[1];
  const int*   src = (const int*)d_in[2];
  const int*   dst = (const int*)d_in[3];
  const float* We1 = (const float*)d_in[4];
  const float* be1 = (const float*)d_in[5];
  const float* We2 = (const float*)d_in[6];
  const float* be2 = (const float*)d_in[7];
  const float* Wn1 = (const float*)d_in[8];
  const float* bn1 = (const float*)d_in[9];
  const float* Wn2 = (const float*)d_in[10];
  const float* bn2 = (const float*)d_in[11];

  float* hout = (float*)d_out;
  float* out_edge = hout + (size_t)N_NODES * NODE_DIM;

  char* ws = (char*)d_ws;
  int*   hist    = (int*)ws;                     // 200,000 B
  int*   off     = (int*)(ws + 200000);          // 200,004 B
  int*   cursor  = (int*)(ws + 400016);          // 200,000 B
  int*   eid     = (int*)(ws + 600016);          // 3,200,000 B (scan partials + fallback)
  int*   csr_src = (int*)(ws + 3800016);         // 3,200,000 B
  int*   csr_dst = (int*)(ws + 7000016);         // 3,200,000 B
  float* e_sum   = (float*)(ws + 10200016);      // 12,800,000 B (f32)
  u16*   w1ef    = (u16*)(ws + 23000016);        // 32,768 B
  u16*   w1st    = (u16*)(ws + 23032784);        // 65,536 B
  u16*   w1dt    = (u16*)(ws + 23098320);        // 65,536 B
  u16*   w2y     = (u16*)(ws + 23163856);        // 32,768 B
  u16*   wn1t    = (u16*)(ws + 23196624);        // 98,304 B
  u16*   wn2t    = (u16*)(ws + 23294928);        // 65,536 B
  float* b2p     = (float*)(ws + 23360464);      // 256 B
  u16*   P_src   = (u16*)(ws + 23360720);        // 25,600,000 B
  u16*   P_dst   = (u16*)(ws + 48960720);        // 25,600,000 B
  u16*   csr_efb = (u16*)(ws + 74560720);        // 102,400,000 B (end ~177 MB)
  const size_t NEED_EFB = 176960720;
  const int efb = (ws_size >= NEED_EFB) ? 1 : 0;

  hipMemsetAsync(hist, 0, 200000, stream);
  prep_weights<<<512, 256, 0, stream>>>(We1, We2, Wn1, Wn2, be2, dst,
                                        w1st, w1dt, w1ef, w2y, wn1t, wn2t,
                                        b2p, hist);
  pgemm_kernel<<<NB_P, 256, 0, stream>>>(nf, w1st, w1dt, be1, P_src, P_dst);
  scanA_kernel<<<NB_SCAN, 256, 0, stream>>>(hist, eid);
  scanB_kernel<<<1, 256, 0, stream>>>(eid, off);
  scanC_kernel<<<NB_SCAN, 256, 0, stream>>>(hist, eid, off, cursor, e_sum);
  if (efb) {
    scatter_kernel<true><<<(N_EDGES + 255) / 256, 256, 0, stream>>>(
        src, dst, ef, cursor, eid, csr_src, csr_dst, csr_efb);
    edge_mlp<true><<<N_EDGES / 128, 256, 0, stream>>>(
        P_src, P_dst, ef, csr_efb, eid, csr_src, csr_dst,
        w1ef, w2y, b2p, e_sum, out_edge);
  } else {
    scatter_kernel<false><<<(N_EDGES + 255) / 256, 256, 0, stream>>>(
        src, dst, ef, cursor, eid, csr_src, csr_dst, csr_efb);
    edge_mlp<false><<<N_EDGES / 128, 256, 0, stream>>>(
        P_src, P_dst, ef, csr_efb, eid, csr_src, csr_dst,
        w1ef, w2y, b2p, e_sum, out_edge);
  }
  node_kernel<<<(N_NODES + 63) / 64, 256, 0, stream>>>(nf, e_sum, hist,
                                                       wn1t, bn1, wn2t, bn2, hout);
}

// Round 15
// 512.513 us; speedup vs baseline: 1.0804x; 1.0804x over previous
//
#include <hip/hip_runtime.h>

#define N_NODES 50000
#define N_EDGES 800000
#define NODE_DIM 128
#define EDGE_DIM 64
#define HIDDEN 256
#define K_N 192   // NODE_DIM + EDGE_DIM

typedef __attribute__((ext_vector_type(8))) short bf16x8;
typedef __attribute__((ext_vector_type(4))) float f32x4;
typedef __attribute__((ext_vector_type(16))) float f32x16;
typedef unsigned short u16;
typedef unsigned int u32;

#define MFMA16 __builtin_amdgcn_mfma_f32_16x16x32_bf16
#define MFMA32 __builtin_amdgcn_mfma_f32_32x32x16_bf16

__device__ inline u16 f2bf(float f) {
  u32 u = __builtin_bit_cast(u32, f);
  u += 0x7fffu + ((u >> 16) & 1u);
  return (u16)(u >> 16);
}
__device__ inline float bf2f(u16 u) {
  u32 x = ((u32)u) << 16;
  return __builtin_bit_cast(float, x);
}
// HW packed f32->bf16 (RNE), lo = a, hi = b
__device__ inline u32 cvt_pk(float a, float b) {
  u32 r;
  asm("v_cvt_pk_bf16_f32 %0, %1, %2" : "=v"(r) : "v"(a), "v"(b));
  return r;
}
__device__ inline void st_bf4(u16* p, float4 v) {
  ushort4 r;
  r.x = f2bf(v.x); r.y = f2bf(v.y); r.z = f2bf(v.z); r.w = f2bf(v.w);
  *reinterpret_cast<ushort4*>(p) = r;
}

// ---------------- streaming: out_edge passthrough + bf16 edge table ----------
// Pure BW kernel: read ef once, write f32 copy (output 1) + bf16 table
// (edge-order, gathered later by eid). 512 MB total traffic.
template<bool EFB>
__global__ __launch_bounds__(256) void convert_kernel(
    const float* __restrict__ ef, float* __restrict__ out_edge,
    u16* __restrict__ efb_edge) {
  const int stride = gridDim.x * blockDim.x;
  const float4* s = reinterpret_cast<const float4*>(ef);
  float4* o = reinterpret_cast<float4*>(out_edge);
  uint2* b = reinterpret_cast<uint2*>(efb_edge);
  for (int g = blockIdx.x * blockDim.x + threadIdx.x;
       g < N_EDGES * 16; g += stride) {
    float4 v = s[g];
    o[g] = v;
    if (EFB) {
      uint2 r;
      r.x = cvt_pk(v.x, v.y);
      r.y = cvt_pk(v.z, v.w);
      b[g] = r;
    }
  }
}

// ---------------- weight prep (+ fused degree histogram) ----------------
__global__ void prep_weights(const float* __restrict__ We1, const float* __restrict__ We2,
                             const float* __restrict__ Wn1, const float* __restrict__ Wn2,
                             const float* __restrict__ be2, const int* __restrict__ dst,
                             u16* __restrict__ w1st, u16* __restrict__ w1dt,
                             u16* __restrict__ w1ef, u16* __restrict__ w2y,
                             u16* __restrict__ wn1t, u16* __restrict__ wn2t,
                             float* __restrict__ b2p, int* __restrict__ hist) {
  const int stride = gridDim.x * blockDim.x;
  const int tid = blockIdx.x * blockDim.x + threadIdx.x;
  for (int i = tid; i < HIDDEN * NODE_DIM; i += stride) {
    int h = i >> 7, k = i & 127;
    w1st[i] = f2bf(We1[k * HIDDEN + h]);
    w1dt[i] = f2bf(We1[(192 + k) * HIDDEN + h]);
  }
  for (int i = tid; i < 8 * 4 * 64 * 8; i += stride) {
    int jj = i & 7;
    int l = (i >> 3) & 63;
    int kb = (i >> 9) & 3;
    int ht = i >> 11;
    int h = ht * 32 + (l & 31);
    int kloc = kb * 16 + (l >> 5) * 8 + jj;
    w1ef[i] = f2bf(We1[(128 + kloc) * HIDDEN + h]);
  }
  for (int i = tid; i < EDGE_DIM * HIDDEN; i += stride) {
    int jj = i & 7;
    int l = (i >> 3) & 63;
    int t2 = (i >> 9) & 1;
    int kb2 = i >> 10;
    int out = t2 * 32 + (l & 31);
    int hi = l >> 5;
    int k = kb2 * 16 + (jj & 3) + 8 * (jj >> 2) + 4 * hi;
    w2y[i] = f2bf(We2[k * EDGE_DIM + out]);
  }
  for (int i = tid; i < HIDDEN * K_N; i += stride) {
    int n = i / K_N, k = i % K_N;
    wn1t[i] = f2bf(Wn1[k * HIDDEN + n]);
  }
  for (int i = tid; i < NODE_DIM * HIDDEN; i += stride) {
    int n = i / HIDDEN, k = i % HIDDEN;
    wn2t[i] = f2bf(Wn2[k * NODE_DIM + n]);
  }
  for (int i = tid; i < EDGE_DIM; i += stride) {
    int t2 = i >> 5, hi = (i >> 4) & 1, r = i & 15;
    b2p[i] = be2[t2 * 32 + (r & 3) + 8 * (r >> 2) + 4 * hi];
  }
  for (int i = tid; i < N_EDGES; i += stride)
    atomicAdd(&hist[dst[i]], 1);
}

// ---------------- P-GEMM (fused: both tables per block) ----------------
// P[n][c], c = hi*128 + ht*16 + r  <->  h = ht*32 + (r&3) + 8*(r>>2) + 4*hi.
#define NB_P 782   // ceil(50000/64)
#define SA_P 136
#define SH   264

__global__ __launch_bounds__(256) void pgemm_kernel(
    const float* __restrict__ nf, const u16* __restrict__ w1st,
    const u16* __restrict__ w1dt, const float* __restrict__ be1,
    u16* __restrict__ P_src, u16* __restrict__ P_dst)
{
  __shared__ u16 A[64 * SA_P];
  __shared__ u16 H[64 * SH];
  const int tid = threadIdx.x;
  const int n0 = blockIdx.x * 64;
  const float4* nf4 = reinterpret_cast<const float4*>(nf);

  #pragma unroll
  for (int p = 0; p < 8; ++p) {
    int i = p * 256 + tid;
    int row = i >> 5, c4 = i & 31;
    int rg = min(n0 + row, N_NODES - 1);
    float4 v = nf4[(size_t)rg * 32 + c4];
    st_bf4(&A[row * SA_P + c4 * 4], v);
  }
  __syncthreads();

  const int wave = tid >> 6, lane = tid & 63;
  const int lr = lane & 15;
  const int lk = (lane >> 4) * 8;

  for (int table = 0; table < 2; ++table) {
    const u16* w = table ? w1dt : w1st;
    u16* P = table ? P_dst : P_src;

    f32x4 acc[4][4] = {};
    #pragma unroll
    for (int kb = 0; kb < 4; ++kb) {
      const int ko = kb * 32 + lk;
      bf16x8 a[4], bb[4];
      #pragma unroll
      for (int mt = 0; mt < 4; ++mt)
        a[mt] = *reinterpret_cast<const bf16x8*>(&A[(mt * 16 + lr) * SA_P + ko]);
      #pragma unroll
      for (int nt = 0; nt < 4; ++nt)
        bb[nt] = *reinterpret_cast<const bf16x8*>(&w[(size_t)(wave * 64 + nt * 16 + lr) * 128 + ko]);
      #pragma unroll
      for (int mt = 0; mt < 4; ++mt)
        #pragma unroll
        for (int nt = 0; nt < 4; ++nt)
          acc[mt][nt] = MFMA16(a[mt], bb[nt], acc[mt][nt], 0, 0, 0);
    }
    __syncthreads();   // H write-after-read across tables

    #pragma unroll
    for (int mt = 0; mt < 4; ++mt)
      #pragma unroll
      for (int nt = 0; nt < 4; ++nt) {
        int col = wave * 64 + nt * 16 + lr;
        float bias = table ? 0.f : be1[col];
        #pragma unroll
        for (int j = 0; j < 4; ++j) {
          int row = mt * 16 + (lane >> 4) * 4 + j;
          H[row * SH + col] = f2bf(acc[mt][nt][j] + bias);  // no relu: pre-act partial
        }
      }
    __syncthreads();

    #pragma unroll
    for (int p = 0; p < 16; ++p) {
      int u = p * 256 + tid;
      int row = u >> 6, cg = u & 63;
      int hi = cg >> 5, ht = (cg >> 2) & 7, q = cg & 3;
      int hbase = ht * 32 + 8 * q + 4 * hi;
      int n = n0 + row;
      if (n < N_NODES) {
        ushort4 v = *reinterpret_cast<const ushort4*>(&H[row * SH + hbase]);
        *reinterpret_cast<ushort4*>(&P[(size_t)n * 256 + cg * 4]) = v;
      }
    }
  }
}

// ---------------- CSR build: 3-phase parallel scan ----------------
#define NB_SCAN 196   // 196*256 = 50176 >= 50000

__global__ void scanA_kernel(const int* __restrict__ hist, int* __restrict__ eid) {
  __shared__ int red[256];
  int gid = blockIdx.x * 256 + threadIdx.x;
  int v = (gid < N_NODES) ? hist[gid] : 0;
  red[threadIdx.x] = v;
  __syncthreads();
  for (int d = 128; d > 0; d >>= 1) {
    if (threadIdx.x < d) red[threadIdx.x] += red[threadIdx.x + d];
    __syncthreads();
  }
  if (threadIdx.x == 0) eid[blockIdx.x] = red[0];   // bsum[b]
}

__global__ void scanB_kernel(int* __restrict__ eid, int* __restrict__ off) {
  __shared__ int ssum[256];
  int tid = threadIdx.x;
  int v = (tid < NB_SCAN) ? eid[tid] : 0;
  ssum[tid] = v;
  __syncthreads();
  for (int d = 1; d < 256; d <<= 1) {
    int t = (tid >= d) ? ssum[tid - d] : 0;
    __syncthreads();
    ssum[tid] += t;
    __syncthreads();
  }
  if (tid < NB_SCAN) eid[256 + tid] = ssum[tid] - v;   // bpre[b] (exclusive)
  if (tid == 255) off[N_NODES] = ssum[255];            // total
}

__global__ void scanC_kernel(const int* __restrict__ hist, const int* __restrict__ eid,
                             int* __restrict__ off, int* __restrict__ cursor,
                             float* __restrict__ e_sum) {
  __shared__ int ssum[256];
  int tid = threadIdx.x;
  int gid = blockIdx.x * 256 + tid;
  int base = eid[256 + blockIdx.x];
  int v = (gid < N_NODES) ? hist[gid] : 0;
  ssum[tid] = v;
  __syncthreads();
  for (int d = 1; d < 256; d <<= 1) {
    int t = (tid >= d) ? ssum[tid - d] : 0;
    __syncthreads();
    ssum[tid] += t;
    __syncthreads();
  }
  if (gid < N_NODES) {
    int o = base + ssum[tid] - v;
    off[gid] = o;
    cursor[gid] = o;
    float4 z = {0.f, 0.f, 0.f, 0.f};
    float4* ez = reinterpret_cast<float4*>(e_sum + (size_t)gid * 64);
    #pragma unroll
    for (int q = 0; q < 16; ++q) ez[q] = z;
  }
}

__global__ void scatter_kernel(const int* __restrict__ src, const int* __restrict__ dst,
                               int* __restrict__ cursor, int* __restrict__ eid,
                               int* __restrict__ csr_src, int* __restrict__ csr_dst) {
  int e = blockIdx.x * blockDim.x + threadIdx.x;
  if (e < N_EDGES) {
    int d = dst[e];
    int pos = atomicAdd(&cursor[d], 1);
    eid[pos] = e;
    csr_src[pos] = src[e];
    csr_dst[pos] = d;
  }
}

// ---------------- edge MLP v12: K=64 split, bf16 eid-gather, no passthrough --
// layer1 = P_src[src] + P_dst[dst] + e @ W1e. efr gathered from the bf16
// edge-order table (128B random rows, half of f32). P gathers pipelined.
template<bool EFB>
__global__ __launch_bounds__(256, 4) void edge_mlp(
    const u16* __restrict__ P_src, const u16* __restrict__ P_dst,
    const float* __restrict__ ef, const u16* __restrict__ efb_edge,
    const int* __restrict__ eid, const int* __restrict__ csr_src,
    const int* __restrict__ csr_dst,
    const u16* __restrict__ w1ef, const u16* __restrict__ w2y,
    const float* __restrict__ b2p,
    float* __restrict__ e_sum)
{
  __shared__ char shmem[33280];                     // 33,280 B (4 blocks/CU ok)
  u16* W1e = reinterpret_cast<u16*>(shmem);         // 32,768 B (phase 1)
  float* bounce = reinterpret_cast<float*>(shmem);  // 128x65 f32 (phase 2, aliased)

  const int tid = threadIdx.x;
  const int wv = tid >> 6, lane = tid & 63;
  const int ecol = lane & 31;     // CSR position within wave tile (D col)
  const int hi = lane >> 5;       // k half
  const int e0 = blockIdx.x * 128;
  const int pos = e0 + wv * 32 + ecol;

  // ---- stage W1e fragments (32KB, once) ----
  {
    const uint4* s = reinterpret_cast<const uint4*>(w1ef);
    uint4* d = reinterpret_cast<uint4*>(W1e);
    #pragma unroll
    for (int j = 0; j < 8; ++j) d[j * 256 + tid] = s[j * 256 + tid];
  }

  // ---- CSR indices (coalesced) ----
  const int e    = eid[pos];
  const int srcn = csr_src[pos];
  const int dstn = csr_dst[pos];   // register; shfl'd in the epilogue

  // ---- edge features -> B-frags (k = kb*16 + hi*8 + jj), K=64 ----
  bf16x8 efr[4];
  if (EFB) {
    const u16* eb = efb_edge + (size_t)e * 64 + hi * 8;   // 128B bf16 row
    #pragma unroll
    for (int kb = 0; kb < 4; ++kb)
      efr[kb] = *reinterpret_cast<const bf16x8*>(eb + kb * 16);
  } else {
    #pragma unroll
    for (int kb = 0; kb < 4; ++kb) {
      const float* ep = ef + (size_t)e * 64 + kb * 16 + hi * 8;
      float4 lo = *reinterpret_cast<const float4*>(ep);
      float4 hv = *reinterpret_cast<const float4*>(ep + 4);
      u32 w[4];
      w[0] = cvt_pk(lo.x, lo.y); w[1] = cvt_pk(lo.z, lo.w);
      w[2] = cvt_pk(hv.x, hv.y); w[3] = cvt_pk(hv.z, hv.w);
      efr[kb] = __builtin_bit_cast(bf16x8, *reinterpret_cast<uint4*>(w));
    }
  }

  __syncthreads();   // W1e staged

  // ---- layer-2 accumulators, bias-initialized ----
  f32x16 acc2[2];
  #pragma unroll
  for (int t2 = 0; t2 < 2; ++t2) {
    const float* bp = b2p + t2 * 32 + hi * 16;
    #pragma unroll
    for (int r = 0; r < 16; ++r) acc2[t2][r] = bp[r];
  }

  const u16* psb = P_src + (size_t)srcn * 256 + hi * 128;
  const u16* pdb = P_dst + (size_t)dstn * 256 + hi * 128;

  // prologue P gather (ht=0)
  bf16x8 pa0 = *reinterpret_cast<const bf16x8*>(psb);
  bf16x8 pa1 = *reinterpret_cast<const bf16x8*>(psb + 8);
  bf16x8 pd0 = *reinterpret_cast<const bf16x8*>(pdb);
  bf16x8 pd1 = *reinterpret_cast<const bf16x8*>(pdb + 8);

  // ---- ht loop: 8 tiles of 32 hidden; P gathers pipelined 1 ahead ----
  #pragma unroll
  for (int ht = 0; ht < 8; ++ht) {
    bf16x8 na0, na1, nd0, nd1;
    if (ht < 7) {
      na0 = *reinterpret_cast<const bf16x8*>(psb + (ht + 1) * 16);
      na1 = *reinterpret_cast<const bf16x8*>(psb + (ht + 1) * 16 + 8);
      nd0 = *reinterpret_cast<const bf16x8*>(pdb + (ht + 1) * 16);
      nd1 = *reinterpret_cast<const bf16x8*>(pdb + (ht + 1) * 16 + 8);
    }

    f32x16 acc;
    #pragma unroll
    for (int r = 0; r < 8; ++r) {
      acc[r]     = bf2f((u16)pa0[r]) + bf2f((u16)pd0[r]);
      acc[8 + r] = bf2f((u16)pa1[r]) + bf2f((u16)pd1[r]);
    }

    // layer 1: K=64 (4 kb), W1e frags from LDS
    #pragma unroll
    for (int kb = 0; kb < 4; ++kb) {
      bf16x8 wf = *reinterpret_cast<const bf16x8*>(W1e + ((ht * 4 + kb) * 64 + lane) * 8);
      acc = MFMA32(wf, efr[kb], acc, 0, 0, 0);
    }

    // layer 2: relu + HW-packed bf16 -> B-frag slots (pi matches D row layout)
    #pragma unroll
    for (int s2 = 0; s2 < 2; ++s2) {
      bf16x8 hf;
      u32* hw = reinterpret_cast<u32*>(&hf);
      #pragma unroll
      for (int m = 0; m < 4; ++m)
        hw[m] = cvt_pk(fmaxf(acc[s2 * 8 + 2 * m], 0.f),
                       fmaxf(acc[s2 * 8 + 2 * m + 1], 0.f));
      #pragma unroll
      for (int t2 = 0; t2 < 2; ++t2) {
        bf16x8 wf2 = *reinterpret_cast<const bf16x8*>(
            w2y + ((size_t)((ht * 2 + s2) * 2 + t2) * 64 + lane) * 8);
        acc2[t2] = MFMA32(wf2, hf, acc2[t2], 0, 0, 0);
      }
    }

    pa0 = na0; pa1 = na1; pd0 = nd0; pd1 = nd1;
  }

  __syncthreads();   // all waves done reading W1e before bounce aliasing

  // ---- f32 message bounce: wave-private rows, stride 65 (conflict-free) ----
  {
    const int lp = wv * 32 + ecol;
    #pragma unroll
    for (int t2 = 0; t2 < 2; ++t2)
      #pragma unroll
      for (int r = 0; r < 16; ++r) {
        int o = t2 * 32 + (r & 3) + 8 * (r >> 2) + 4 * hi;
        bounce[lp * 65 + o] = acc2[t2][r];
      }
  }
  // same-wave ds_write -> ds_read: lgkmcnt ordering suffices (no barrier)

  // ---- wave-uniform run-reduction over this wave's 32 positions ----
  {
    const int d = lane;            // dim 0..63
    const int base = wv * 32;      // strip of 32 local positions
    float s = bounce[base * 65 + d];
    int cur = __shfl(dstn, 0, 64);
    #pragma unroll 4
    for (int i = 1; i < 32; ++i) {
      int nx = __shfl(dstn, i, 64);   // wave-uniform
      float v = bounce[(base + i) * 65 + d];
      if (nx == cur) {
        s += v;
      } else {
        atomicAdd(&e_sum[(size_t)cur * 64 + d], s);
        cur = nx;
        s = v;
      }
    }
    atomicAdd(&e_sum[(size_t)cur * 64 + d], s);
  }
}

// ---------------- node MLP + degree gate ----------------
#define SA_N 200

__global__ __launch_bounds__(256) void node_kernel(
    const float* __restrict__ nf, const float* __restrict__ e_sum,
    const int* __restrict__ hist,
    const u16* __restrict__ w1, const float* __restrict__ b1,
    const u16* __restrict__ w2, const float* __restrict__ b2,
    float* __restrict__ hout)
{
  __shared__ u16 A[64 * SH];
  const int tid = threadIdx.x;
  const int n0 = blockIdx.x * 64;

  const float4* nf4 = reinterpret_cast<const float4*>(nf);
  const float4* es4 = reinterpret_cast<const float4*>(e_sum);

  #pragma unroll
  for (int p = 0; p < 8; ++p) {
    int i = p * 256 + tid;
    int row = i >> 5, c4 = i & 31;
    int rg = min(n0 + row, N_NODES - 1);
    float4 v = nf4[(size_t)rg * 32 + c4];
    st_bf4(&A[row * SA_N + c4 * 4], v);
  }
  #pragma unroll
  for (int p = 0; p < 4; ++p) {
    int i = p * 256 + tid;
    int row = i >> 4, c4 = i & 15;
    int rg = min(n0 + row, N_NODES - 1);
    float4 v = es4[(size_t)rg * 16 + c4];
    st_bf4(&A[row * SA_N + 128 + c4 * 4], v);
  }
  __syncthreads();

  const int wave = tid >> 6, lane = tid & 63;
  const int lr = lane & 15;
  const int lk = (lane >> 4) * 8;

  f32x4 acc[4][4] = {};
  for (int kb = 0; kb < K_N / 32; ++kb) {
    const int ko = kb * 32 + lk;
    bf16x8 a[4], b[4];
    #pragma unroll
    for (int mt = 0; mt < 4; ++mt)
      a[mt] = *reinterpret_cast<const bf16x8*>(&A[(mt * 16 + lr) * SA_N + ko]);
    #pragma unroll
    for (int nt = 0; nt < 4; ++nt)
      b[nt] = *reinterpret_cast<const bf16x8*>(&w1[(size_t)(wave * 64 + nt * 16 + lr) * K_N + ko]);
    #pragma unroll
    for (int mt = 0; mt < 4; ++mt)
      #pragma unroll
      for (int nt = 0; nt < 4; ++nt)
        acc[mt][nt] = MFMA16(a[mt], b[nt], acc[mt][nt], 0, 0, 0);
  }
  __syncthreads();

  u16* H = A;
  #pragma unroll
  for (int mt = 0; mt < 4; ++mt)
    #pragma unroll
    for (int nt = 0; nt < 4; ++nt) {
      int col = wave * 64 + nt * 16 + lr;
      float bias = b1[col];
      #pragma unroll
      for (int j = 0; j < 4; ++j) {
        int row = mt * 16 + (lane >> 4) * 4 + j;
        float h = acc[mt][nt][j] + bias;
        H[row * SH + col] = f2bf(h > 0.f ? h : 0.f);
      }
    }
  __syncthreads();

  f32x4 acc2[8] = {};
  for (int kb = 0; kb < HIDDEN / 32; ++kb) {
    const int ko = kb * 32 + lk;
    bf16x8 a = *reinterpret_cast<const bf16x8*>(&H[(wave * 16 + lr) * SH + ko]);
    #pragma unroll
    for (int nt = 0; nt < 8; ++nt) {
      bf16x8 b = *reinterpret_cast<const bf16x8*>(&w2[(size_t)(nt * 16 + lr) * HIDDEN + ko]);
      acc2[nt] = MFMA16(a, b, acc2[nt], 0, 0, 0);
    }
  }
  #pragma unroll
  for (int nt = 0; nt < 8; ++nt) {
    int col = nt * 16 + lr;
    float bias = b2[col];
    #pragma unroll
    for (int j = 0; j < 4; ++j) {
      int row = wave * 16 + (lane >> 4) * 4 + j;
      int rg = n0 + row;
      if (rg < N_NODES) {
        float v = acc2[nt][j] + bias;
        hout[(size_t)rg * NODE_DIM + col] =
            (hist[rg] != 0) ? v : nf[(size_t)rg * NODE_DIM + col];
      }
    }
  }
}

// ---------------- launcher ----------------
extern "C" void kernel_launch(void* const* d_in, const int* in_sizes, int n_in,
                              void* d_out, int out_size, void* d_ws, size_t ws_size,
                              hipStream_t stream) {
  const float* nf  = (const float*)d_in[0];
  const float* ef  = (const float*)d_in[1];
  const int*   src = (const int*)d_in[2];
  const int*   dst = (const int*)d_in[3];
  const float* We1 = (const float*)d_in[4];
  const float* be1 = (const float*)d_in[5];
  const float* We2 = (const float*)d_in[6];
  const float* be2 = (const float*)d_in[7];
  const float* Wn1 = (const float*)d_in[8];
  const float* bn1 = (const float*)d_in[9];
  const float* Wn2 = (const float*)d_in[10];
  const float* bn2 = (const float*)d_in[11];

  float* hout = (float*)d_out;
  float* out_edge = hout + (size_t)N_NODES * NODE_DIM;

  char* ws = (char*)d_ws;
  int*   hist    = (int*)ws;                     // 200,000 B
  int*   off     = (int*)(ws + 200000);          // 200,004 B
  int*   cursor  = (int*)(ws + 400016);          // 200,000 B
  int*   eid     = (int*)(ws + 600016);          // 3,200,000 B (scan partials early)
  int*   csr_src = (int*)(ws + 3800016);         // 3,200,000 B
  int*   csr_dst = (int*)(ws + 7000016);         // 3,200,000 B
  float* e_sum   = (float*)(ws + 10200016);      // 12,800,000 B (f32)
  u16*   w1ef    = (u16*)(ws + 23000016);        // 32,768 B
  u16*   w1st    = (u16*)(ws + 23032784);        // 65,536 B
  u16*   w1dt    = (u16*)(ws + 23098320);        // 65,536 B
  u16*   w2y     = (u16*)(ws + 23163856);        // 32,768 B
  u16*   wn1t    = (u16*)(ws + 23196624);        // 98,304 B
  u16*   wn2t    = (u16*)(ws + 23294928);        // 65,536 B
  float* b2p     = (float*)(ws + 23360464);      // 256 B
  u16*   P_src   = (u16*)(ws + 23360720);        // 25,600,000 B
  u16*   P_dst   = (u16*)(ws + 48960720);        // 25,600,000 B
  u16*   efb_edge= (u16*)(ws + 74560720);        // 102,400,000 B (end ~177 MB)
  const size_t NEED_EFB = 176960720;
  const int efb = (ws_size >= NEED_EFB) ? 1 : 0;

  hipMemsetAsync(hist, 0, 200000, stream);
  prep_weights<<<512, 256, 0, stream>>>(We1, We2, Wn1, Wn2, be2, dst,
                                        w1st, w1dt, w1ef, w2y, wn1t, wn2t,
                                        b2p, hist);
  if (efb) convert_kernel<true><<<2048, 256, 0, stream>>>(ef, out_edge, efb_edge);
  else     convert_kernel<false><<<2048, 256, 0, stream>>>(ef, out_edge, efb_edge);
  pgemm_kernel<<<NB_P, 256, 0, stream>>>(nf, w1st, w1dt, be1, P_src, P_dst);
  scanA_kernel<<<NB_SCAN, 256, 0, stream>>>(hist, eid);
  scanB_kernel<<<1, 256, 0, stream>>>(eid, off);
  scanC_kernel<<<NB_SCAN, 256, 0, stream>>>(hist, eid, off, cursor, e_sum);
  scatter_kernel<<<(N_EDGES + 255) / 256, 256, 0, stream>>>(src, dst, cursor, eid,
                                                            csr_src, csr_dst);
  if (efb) {
    edge_mlp<true><<<N_EDGES / 128, 256, 0, stream>>>(
        P_src, P_dst, ef, efb_edge, eid, csr_src, csr_dst,
        w1ef, w2y, b2p, e_sum);
  } else {
    edge_mlp<false><<<N_EDGES / 128, 256, 0, stream>>>(
        P_src, P_dst, ef, efb_edge, eid, csr_src, csr_dst,
        w1ef, w2y, b2p, e_sum);
  }
  node_kernel<<<(N_NODES + 63) / 64, 256, 0, stream>>>(nf, e_sum, hist,
                                                       wn1t, bn1, wn2t, bn2, hout);
}